// Round 13
// baseline (1399.800 us; speedup 1.0000x reference)
//
#include <hip/hip_runtime.h>
#include <hip/hip_bf16.h>
#include <math.h>

#define HW   511
#define HW2  261121      // 511*511
#define MM   510
#define MM2  260100      // 510*510
#define NN   512
#define NN2  262144      // 512*512
#define PI_D 3.14159265358979323846

typedef __attribute__((ext_vector_type(8))) short short8;
typedef __attribute__((ext_vector_type(4))) float float4v;

__device__ __forceinline__ float bf2f(const __hip_bfloat16 v) { return __bfloat162float(v); }

__device__ __forceinline__ float ldin(const void* p, long i, int mode)
{
    return mode ? ((const float*)p)[i] : bf2f(((const __hip_bfloat16*)p)[i]);
}

__device__ __forceinline__ short f2bf(float v)
{
    unsigned u = __builtin_bit_cast(unsigned, v);
    u += 0x7FFF + ((u >> 16) & 1);
    return (short)(u >> 16);
}
__device__ __forceinline__ float bfs2f(short s)
{
    unsigned u = ((unsigned)(unsigned short)s) << 16;
    return __builtin_bit_cast(float, u);
}

__global__ void detect_kernel(const void* __restrict__ f, int* __restrict__ mode)
{
    __shared__ int cnt;
    if (threadIdx.x == 0) cnt = 0;
    __syncthreads();
    float v = ((const float*)f)[threadIdx.x];
    float a = fabsf(v);
    int sane = (isfinite(v) && a > 1e-6f && a < 100.f) ? 1 : 0;
    atomicAdd(&cnt, sane);
    __syncthreads();
    if (threadIdx.x == 0) mode[0] = (cnt >= 128) ? 1 : 0;
}

__global__ void sentinel_kernel(float* __restrict__ out) { out[0] = 0.25f; }

__global__ void zerod_kernel(double* __restrict__ p)
{
    if (threadIdx.x < 2) p[threadIdx.x] = 0.0;
}

// ---------------- basis matrices, directly as bf16 hi/lo planes ----------------
__global__ void basisHL_kernel(short* __restrict__ SfH, short* __restrict__ SfL,
                               short* __restrict__ CSH, short* __restrict__ CSL,
                               short* __restrict__ CS2H, short* __restrict__ CS2L)
{
    int idx = blockIdx.x * 256 + threadIdx.x;
    if (idx < 511 * 512) {
        int a = idx / 512, m = idx % 512;
        float v = 0.f;
        if (m < 510) v = (float)sin(PI_D * (double)(a - 255) * (double)(m + 1) / 511.0);
        short h = f2bf(v);
        SfH[idx] = h; SfL[idx] = f2bf(v - bfs2f(h));
    }
    if (idx < 510 * 1024) {
        int p = idx / 1024, a = idx % 1024;
        float c = 0.f, c2 = 0.f;
        if (a < 1022) {
            if (a < 511) {
                double ang = PI_D * (double)p * (double)(a - 255) / 511.0;
                c = (float)cos(ang); c2 = (float)(-sin(ang));
            } else {
                double ang = PI_D * (double)p * (double)(a - 511 - 255) / 511.0;
                c = (float)sin(ang); c2 = (float)cos(ang);
            }
        }
        short h = f2bf(c);
        CSH[idx] = h; CSL[idx] = f2bf(c - bfs2f(h));
        h = f2bf(c2);
        CS2H[idx] = h; CS2L[idx] = f2bf(c2 - bfs2f(h));
    }
}

__global__ void zerocol_kernel(short* __restrict__ XH, short* __restrict__ XL, long csb)
{
    int z = blockIdx.x;
    int t = threadIdx.x;
    if (t < 510) {
        XH[(long)z * csb + (long)t * 1024 + 1023] = 0;
        XL[(long)z * csb + (long)t * 1024 + 1023] = 0;
    }
}

// ---------------- 5-point stencil A ----------------
__device__ __forceinline__ float computeA(const float* __restrict__ xb,
                                          const void* __restrict__ cb,
                                          int p, int q, int mode)
{
    if (p < 1 || p > 510 || q < 1 || q > 510) return 0.f;
    int i = p - 1, j = q - 1;
    float a   = ldin(cb, (long)i * MM + j, mode);
    float aw  = ldin(cb, (long)i * MM + (j > 0 ? j - 1 : 0), mode);
    float ae  = ldin(cb, (long)i * MM + (j < MM - 1 ? j + 1 : MM - 1), mode);
    float an  = ldin(cb, (long)(i < MM - 1 ? i + 1 : MM - 1) * MM + j, mode);
    float as_ = ldin(cb, (long)(i > 0 ? i - 1 : 0) * MM + j, mode);
    float sw = -2.f * aw  * a / (aw  + a);
    float se = -2.f * ae  * a / (ae  + a);
    float sn = -2.f * an  * a / (an  + a);
    float ss = -2.f * as_ * a / (as_ + a);
    float sc = -(sw + se + sn + ss);
    return ss * xb[(p - 1) * NN + q] + sw * xb[p * NN + q - 1] + sc * xb[p * NN + q]
         + se * xb[p * NN + q + 1] + sn * xb[(p + 1) * NN + q];
}

__global__ void initx_kernel(float* __restrict__ x, const void* __restrict__ f,
                             int b0, const int* __restrict__ dmode)
{
    int mode = dmode[0];
    int q = blockIdx.x * 32 + threadIdx.x;
    int p = blockIdx.y * 8 + threadIdx.y;
    int bz = blockIdx.z;
    int b = b0 + bz;
    if (p >= NN || q >= NN) return;
    const char* fc = (const char*)f + ((long)b * NN2 << (mode + 1));
    x[(long)bz * NN2 + p * NN + q] = 0.078125f * ldin(fc, (long)p * NN + q, mode);
}

__global__ void rich_kernel(const float* __restrict__ xin, float* __restrict__ xout,
                            const void* __restrict__ f, const void* __restrict__ coef,
                            int b0, const int* __restrict__ dmode)
{
    int mode = dmode[0];
    int q = blockIdx.x * 32 + threadIdx.x;
    int p = blockIdx.y * 8 + threadIdx.y;
    int bz = blockIdx.z;
    int b = b0 + bz;
    if (p >= NN || q >= NN) return;
    long xo = (long)bz * NN2;
    const char* cc = (const char*)coef + ((long)b * MM2 << (mode + 1));
    const char* fc = (const char*)f + ((long)b * NN2 << (mode + 1));
    float Ax = computeA(xin + xo, cc, p, q, mode);
    float fv = ldin(fc, (long)p * NN + q, mode);
    xout[xo + p * NN + q] = xin[xo + p * NN + q] + 0.078125f * (fv - Ax);
}

__global__ void resid_kernel(const float* __restrict__ x,
                             const void* __restrict__ f, const void* __restrict__ coef,
                             float* __restrict__ r1, int b0, const int* __restrict__ dmode)
{
    int mode = dmode[0];
    int j = blockIdx.x * 32 + threadIdx.x;
    int i = blockIdx.y * 8 + threadIdx.y;
    int bz = blockIdx.z;
    int b = b0 + bz;
    if (i >= MM || j >= MM) return;
    int p = i + 1, q = j + 1;
    const char* cc = (const char*)coef + ((long)b * MM2 << (mode + 1));
    const char* fc = (const char*)f + ((long)b * NN2 << (mode + 1));
    float Ax = computeA(x + (long)bz * NN2, cc, p, q, mode);
    r1[(long)bz * MM2 + i * MM + j] = ldin(fc, (long)p * NN + q, mode) - Ax;
}

__global__ void update_kernel(float* __restrict__ x,
                              const void* __restrict__ coef,
                              const float* __restrict__ F1, const float* __restrict__ F2,
                              int b0, const int* __restrict__ dmode)
{
    int mode = dmode[0];
    int j = blockIdx.x * 32 + threadIdx.x;
    int i = blockIdx.y * 8 + threadIdx.y;
    int bz = blockIdx.z;
    int b = b0 + bz;
    if (i >= MM || j >= MM) return;
    float cf = ldin(coef, (long)b * MM2 + i * MM + j, mode);
    long o = (long)bz * MM2 + i * MM + j;
    float e = (cf < 1.0f) ? (F1[o] / cf) : (F2[o] * cf);
    x[(long)bz * NN2 + (i + 1) * NN + (j + 1)] += e;
}

__global__ void norm_kernel(const float* __restrict__ x,
                            const void* __restrict__ f, const void* __restrict__ coef,
                            double* __restrict__ pb, int b0, const int* __restrict__ dmode)
{
    int mode = dmode[0];
    int q = blockIdx.x * 32 + threadIdx.x;
    int p = blockIdx.y * 8 + threadIdx.y;
    int bz = blockIdx.z;
    int b = b0 + bz;
    double r2 = 0.0, f2 = 0.0;
    if (p < NN && q < NN) {
        const char* cc = (const char*)coef + ((long)b * MM2 << (mode + 1));
        const char* fc = (const char*)f + ((long)b * NN2 << (mode + 1));
        float Ax = computeA(x + (long)bz * NN2, cc, p, q, mode);
        float fv = ldin(fc, (long)p * NN + q, mode);
        float rv = fv - Ax;
        r2 = (double)rv * (double)rv;
        f2 = (double)fv * (double)fv;
    }
    for (int off = 32; off > 0; off >>= 1) {
        r2 += __shfl_down(r2, off, 64);
        f2 += __shfl_down(f2, off, 64);
    }
    __shared__ double sr[4], sf2[4];
    int tid = threadIdx.y * 32 + threadIdx.x;
    int wid = tid >> 6, lane = tid & 63;
    if (lane == 0) { sr[wid] = r2; sf2[wid] = f2; }
    __syncthreads();
    if (tid == 0) {
        long blk = ((long)blockIdx.z * gridDim.y + blockIdx.y) * gridDim.x + blockIdx.x;
        pb[2 * blk]     = sr[0] + sr[1] + sr[2] + sr[3];
        pb[2 * blk + 1] = sf2[0] + sf2[1] + sf2[2] + sf2[3];
    }
}

__global__ void reduce_kernel(const double* __restrict__ pb, long nblk, double* __restrict__ acc)
{
    double r2 = 0.0, f2 = 0.0;
    for (long i = threadIdx.x; i < nblk; i += 256) {
        r2 += pb[2 * i];
        f2 += pb[2 * i + 1];
    }
    for (int off = 32; off > 0; off >>= 1) {
        r2 += __shfl_down(r2, off, 64);
        f2 += __shfl_down(f2, off, 64);
    }
    __shared__ double sr[4], sf2[4];
    int wid = threadIdx.x >> 6, lane = threadIdx.x & 63;
    if (lane == 0) { sr[wid] = r2; sf2[wid] = f2; }
    __syncthreads();
    if (threadIdx.x == 0) {
        acc[0] += sr[0] + sr[1] + sr[2] + sr[3];
        acc[1] += sf2[0] + sf2[1] + sf2[2] + sf2[3];
    }
}

__global__ void finalize_kernel(const double* __restrict__ acc, float* __restrict__ out)
{
    out[0] = (float)sqrt(acc[0] / acc[1]);
}

// ---------------- fused transpose + hi/lo split ----------------
__global__ void transposeHL_kernel(const float* __restrict__ in,
                                   short* __restrict__ H, short* __restrict__ L,
                                   int R, int C, int ldin, int ldk, int kofs, int Rpad,
                                   long isb, long osb)
{
    __shared__ float t[32][33];
    int z = blockIdx.z;
    in += (long)z * isb;
    H += (long)z * osb + kofs;
    L += (long)z * osb + kofs;
    int c0 = blockIdx.x * 32, r0 = blockIdx.y * 32;
    for (int i = threadIdx.y; i < 32; i += 8) {
        int r = r0 + i, c = c0 + threadIdx.x;
        t[i][threadIdx.x] = (r < R && c < C) ? in[(long)r * ldin + c] : 0.f;
    }
    __syncthreads();
    for (int i = threadIdx.y; i < 32; i += 8) {
        int c = c0 + i, r = r0 + threadIdx.x;
        if (c < C && r < Rpad) {
            float v = t[threadIdx.x][i];
            short h = f2bf(v);
            H[(long)c * ldk + r] = h;
            L[(long)c * ldk + r] = f2bf(v - bfs2f(h));
        }
    }
}

// ---------------- MFMA GEMM on precomputed hi/lo planes ----------------
#define GM 64
#define GN 64
#define GK2 64
#define LK2 72
__global__ __launch_bounds__(256) void gemm_hl(
    const short* __restrict__ AH, const short* __restrict__ AL, int ldaS,
    const short* __restrict__ BH, const short* __restrict__ BL, int ldbS,
    float* __restrict__ C, int ldc,
    short* __restrict__ CH, short* __restrict__ CL, int ldcS, int Npad,
    int M, int N, int Kpad,
    long asb, long bsb, long csb, float alpha, int outHL)
{
    int z = blockIdx.z;
    AH += (long)z * asb; AL += (long)z * asb;
    BH += (long)z * bsb; BL += (long)z * bsb;
    if (outHL) { CH += (long)z * csb; CL += (long)z * csb; }
    else       { C  += (long)z * csb; }
    __shared__ short Ah[GM * LK2], Al[GM * LK2], Bh[GN * LK2], Bl[GN * LK2];
    int tid = threadIdx.x;
    int wave = tid >> 6, lane = tid & 63;
    int wm = (wave & 1) * 32, wn = (wave >> 1) * 32;
    int lr = lane & 15, lq = lane >> 4;
    int m0 = blockIdx.y * GM, n0 = blockIdx.x * GN;
    int row = tid >> 2, kk = (tid & 3) * 16;
    float4v acc[2][2] = {};
    short8 z8 = {};

    for (int k0 = 0; k0 < Kpad; k0 += GK2) {
        {
            short8 h0 = z8, h1 = z8, l0 = z8, l1 = z8;
            if (m0 + row < M) {
                long o = (long)(m0 + row) * ldaS + k0 + kk;
                h0 = *(const short8*)&AH[o]; h1 = *(const short8*)&AH[o + 8];
                l0 = *(const short8*)&AL[o]; l1 = *(const short8*)&AL[o + 8];
            }
            *(short8*)&Ah[row * LK2 + kk]     = h0;
            *(short8*)&Ah[row * LK2 + kk + 8] = h1;
            *(short8*)&Al[row * LK2 + kk]     = l0;
            *(short8*)&Al[row * LK2 + kk + 8] = l1;
        }
        {
            short8 h0 = z8, h1 = z8, l0 = z8, l1 = z8;
            if (n0 + row < N) {
                long o = (long)(n0 + row) * ldbS + k0 + kk;
                h0 = *(const short8*)&BH[o]; h1 = *(const short8*)&BH[o + 8];
                l0 = *(const short8*)&BL[o]; l1 = *(const short8*)&BL[o + 8];
            }
            *(short8*)&Bh[row * LK2 + kk]     = h0;
            *(short8*)&Bh[row * LK2 + kk + 8] = h1;
            *(short8*)&Bl[row * LK2 + kk]     = l0;
            *(short8*)&Bl[row * LK2 + kk + 8] = l1;
        }
        __syncthreads();
        #pragma unroll
        for (int ks = 0; ks < GK2; ks += 32) {
            short8 ah[2], al[2], bh[2], bl[2];
            #pragma unroll
            for (int mt = 0; mt < 2; ++mt) {
                int mloc = wm + mt * 16 + lr;
                ah[mt] = *(const short8*)&Ah[mloc * LK2 + ks + lq * 8];
                al[mt] = *(const short8*)&Al[mloc * LK2 + ks + lq * 8];
            }
            #pragma unroll
            for (int nt = 0; nt < 2; ++nt) {
                int nloc = wn + nt * 16 + lr;
                bh[nt] = *(const short8*)&Bh[nloc * LK2 + ks + lq * 8];
                bl[nt] = *(const short8*)&Bl[nloc * LK2 + ks + lq * 8];
            }
            #pragma unroll
            for (int mt = 0; mt < 2; ++mt)
                #pragma unroll
                for (int nt = 0; nt < 2; ++nt) {
                    acc[mt][nt] = __builtin_amdgcn_mfma_f32_16x16x32_bf16(ah[mt], bh[nt], acc[mt][nt], 0, 0, 0);
                    acc[mt][nt] = __builtin_amdgcn_mfma_f32_16x16x32_bf16(ah[mt], bl[nt], acc[mt][nt], 0, 0, 0);
                    acc[mt][nt] = __builtin_amdgcn_mfma_f32_16x16x32_bf16(al[mt], bh[nt], acc[mt][nt], 0, 0, 0);
                }
        }
        __syncthreads();
    }
    #pragma unroll
    for (int mt = 0; mt < 2; ++mt)
        #pragma unroll
        for (int nt = 0; nt < 2; ++nt)
            #pragma unroll
            for (int r = 0; r < 4; ++r) {
                int gm = m0 + wm + mt * 16 + lq * 4 + r;
                int gn = n0 + wn + nt * 16 + lr;
                if (gm >= M) continue;
                if (!outHL) {
                    if (gn < N) C[(long)gm * ldc + gn] = alpha * acc[mt][nt][r];
                } else {
                    if (gn < Npad) {
                        float v = (gn < N) ? alpha * acc[mt][nt][r] : 0.f;
                        short h = f2bf(v);
                        CH[(long)gm * ldcS + gn] = h;
                        CL[(long)gm * ldcS + gn] = f2bf(v - bfs2f(h));
                    }
                }
            }
}

// ---------------- FUSED conv chain: 1 -> 4 -> 4 -> 1 (+theta) in one kernel ----------------
// Block (64,4) -> 64x8 output tile. All intermediates in LDS.
// input tile 70x14 (halo 3), mid1 68x12 x4ch (halo 2), mid2 66x10 x4ch (halo 1).
// mid2 aliases the input region (input dead after conv1). Boundary positions of
// mid1/mid2 outside the 511x511 image are zeroed (per-stage zero padding semantics).
// INK: 0 = real planar input, 2 = planar complex input (in/in2).
// TMODE: 0 normal weights, 1 conj-transposed. HASTH: multiply theta after conv3.
template<int INK, int TMODE, int HASTH>
__global__ __launch_bounds__(256, 3) void cconv_chain(
    const float* __restrict__ in, const float* __restrict__ in2,
    const void* __restrict__ w1r, const void* __restrict__ w1i,
    const void* __restrict__ w2r, const void* __restrict__ w2i,
    const void* __restrict__ w3r, const void* __restrict__ w3i,
    float* __restrict__ outR, float* __restrict__ outI,
    const void* __restrict__ thr, const void* __restrict__ thi,
    long in_bs, long out_bs, int b0, const int* __restrict__ dmode)
{
    int mode = dmode[0];
    int bz = blockIdx.z, b = b0 + bz;
    __shared__ alignas(16) char smem[48960];
    float2* reg0 = (float2*)smem;               // input tile [14][70], later mid2 [4][10][66]
    float2* mid1 = (float2*)(smem + 21120);     // [4][12][68]
    float2* wts  = (float2*)(smem + 47232);     // 216: w1s[t*4+o], w2s[36+(i*9+t)*4+o], w3s[180+i*9+t]
    int tid = threadIdx.y * 64 + threadIdx.x;
    int x0 = blockIdx.x * 64, y0 = blockIdx.y * 8;

    // ---- stage weights ----
    if (tid < 216) {
        int o, i, ci, co;
        const void *wr, *wi;
        int t;
        if (tid < 36)       { o = tid & 3; t = tid >> 2; i = 0; ci = 1; co = 4; wr = w1r; wi = w1i; }
        else if (tid < 180) { int r = tid - 36; o = r & 3; int it = r >> 2; t = it % 9; i = it / 9; ci = 4; co = 4; wr = w2r; wi = w2i; }
        else                { int r = tid - 180; t = r % 9; i = r / 9; o = 0; ci = 4; co = 1; wr = w3r; wi = w3i; }
        int dy = t / 3, dx = t % 3;
        float rr, im;
        if (!TMODE) {
            long idx = (((long)b * co + o) * ci + i) * 9 + t;
            rr = ldin(wr, idx, mode); im = ldin(wi, idx, mode);
        } else {
            long idx = (((long)b * ci + i) * co + o) * 9 + dx * 3 + dy;
            rr = ldin(wr, idx, mode); im = -ldin(wi, idx, mode);
        }
        float2 wv; wv.x = rr; wv.y = im;
        wts[tid] = wv;
    }

    // ---- stage input tile 70x14, halo 3, zero-padded ----
    {
        const float* pr = in + (long)bz * in_bs;
        const float* pi = (INK == 2) ? (in2 + (long)bz * in_bs) : nullptr;
        for (int idx = tid; idx < 980; idx += 256) {
            int py = idx / 70, px = idx % 70;
            int gy = y0 - 3 + py, gx = x0 - 3 + px;
            float2 v; v.x = 0.f; v.y = 0.f;
            if (gy >= 0 && gy < HW && gx >= 0 && gx < HW) {
                long gi = (long)gy * HW + gx;
                v.x = pr[gi];
                if (INK == 2) v.y = pi[gi];
            }
            reg0[idx] = v;
        }
    }
    __syncthreads();

    // ---- conv1: 1 -> 4, mid1 tile 68x12, origin (y0-2, x0-2) ----
    #pragma unroll 1
    for (int o = 0; o < 4; ++o) {
        float2 w1reg[9];
        #pragma unroll
        for (int k = 0; k < 9; ++k) w1reg[k] = wts[k * 4 + o];
        for (int idx = tid; idx < 816; idx += 256) {
            int py = idx / 68, px = idx % 68;
            float ar = 0.f, ai = 0.f;
            #pragma unroll
            for (int dy = 0; dy < 3; ++dy)
                #pragma unroll
                for (int dx = 0; dx < 3; ++dx) {
                    float2 v = reg0[(py + dy) * 70 + px + dx];
                    float2 wv = w1reg[dy * 3 + dx];
                    ar += v.x * wv.x; ai += v.x * wv.y;
                    if (INK == 2) { ar -= v.y * wv.y; ai += v.y * wv.x; }
                }
            int gy = y0 - 2 + py, gx = x0 - 2 + px;
            if (gy < 0 || gy >= HW || gx < 0 || gx >= HW) { ar = 0.f; ai = 0.f; }
            float2 mv; mv.x = ar; mv.y = ai;
            mid1[(o * 12 + py) * 68 + px] = mv;
        }
    }
    __syncthreads();

    // ---- conv2: 4 -> 4, mid2 tile 66x10 (overwrites input region), origin (y0-1, x0-1) ----
    #pragma unroll 1
    for (int o = 0; o < 4; ++o) {
        float2 w2reg[36];
        #pragma unroll
        for (int k = 0; k < 36; ++k) w2reg[k] = wts[36 + k * 4 + o];
        for (int idx = tid; idx < 660; idx += 256) {
            int py = idx / 66, px = idx % 66;
            float ar = 0.f, ai = 0.f;
            #pragma unroll
            for (int i = 0; i < 4; ++i)
                #pragma unroll
                for (int dy = 0; dy < 3; ++dy)
                    #pragma unroll
                    for (int dx = 0; dx < 3; ++dx) {
                        float2 v = mid1[(i * 12 + py + dy) * 68 + px + dx];
                        float2 wv = w2reg[i * 9 + dy * 3 + dx];
                        ar += v.x * wv.x - v.y * wv.y;
                        ai += v.x * wv.y + v.y * wv.x;
                    }
            int gy = y0 - 1 + py, gx = x0 - 1 + px;
            if (gy < 0 || gy >= HW || gx < 0 || gx >= HW) { ar = 0.f; ai = 0.f; }
            float2 mv; mv.x = ar; mv.y = ai;
            reg0[(o * 10 + py) * 66 + px] = mv;
        }
    }
    __syncthreads();

    // ---- conv3: 4 -> 1 (+theta), out tile 64x8 ----
    {
        float2 w3reg[36];
        #pragma unroll
        for (int k = 0; k < 36; ++k) w3reg[k] = wts[180 + k];
        for (int idx = tid; idx < 512; idx += 256) {
            int py = idx >> 6, px = idx & 63;
            int gy = y0 + py, gx = x0 + px;
            if (gy >= HW || gx >= HW) continue;
            float ar = 0.f, ai = 0.f;
            #pragma unroll
            for (int i = 0; i < 4; ++i)
                #pragma unroll
                for (int dy = 0; dy < 3; ++dy)
                    #pragma unroll
                    for (int dx = 0; dx < 3; ++dx) {
                        float2 v = reg0[(i * 10 + py + dy) * 66 + px + dx];
                        float2 wv = w3reg[i * 9 + dy * 3 + dx];
                        ar += v.x * wv.x - v.y * wv.y;
                        ai += v.x * wv.y + v.y * wv.x;
                    }
            if (HASTH) {
                float tr = ldin(thr, (long)b * HW2 + (long)gy * HW + gx, mode);
                float ti = ldin(thi, (long)b * HW2 + (long)gy * HW + gx, mode);
                float nr = ar * tr - ai * ti, ni = ar * ti + ai * tr;
                ar = nr; ai = ni;
            }
            long oo = (long)bz * out_bs + (long)gy * HW + gx;
            outR[oo] = ar;
            outI[oo] = ai;
        }
    }
}

extern "C" void kernel_launch(void* const* d_in, const int* in_sizes, int n_in,
                              void* d_out, int out_size, void* d_ws, size_t ws_size,
                              hipStream_t stream)
{
    const void* f    = d_in[0];
    const void* coef = d_in[1];
    const void* W1r[2] = {d_in[2],  d_in[8]};
    const void* W1i[2] = {d_in[3],  d_in[9]};
    const void* W2r[2] = {d_in[4],  d_in[10]};
    const void* W2i[2] = {d_in[5],  d_in[11]};
    const void* W3r[2] = {d_in[6],  d_in[12]};
    const void* W3i[2] = {d_in[7],  d_in[13]};
    const void* THr[2] = {d_in[14], d_in[16]};
    const void* THi[2] = {d_in[15], d_in[17]};

    sentinel_kernel<<<1, 64, 0, stream>>>((float*)d_out);

    // ---- ws accounting ----
    const size_t PERSIST = 1330000;
    const size_t PERB    = 4300000;
    size_t ws_floats = ws_size / sizeof(float);
    int cb = 8;
    while (cb > 1 && PERSIST + (size_t)cb * PERB > ws_floats) cb >>= 1;

    float* ws = (float*)d_ws;
    size_t off = 0;
    auto alloc = [&](size_t n) { size_t o = off; off += (n + 63) & ~(size_t)63; return ws + o; };
    auto salloc = [&](size_t nshorts) { return (short*)alloc((nshorts + 1) / 2); };
    double* acc  = (double*)alloc(64);
    int*   dmode = (int*)alloc(64);
    double* pb   = (double*)alloc(32768);
    short* SfH  = salloc(511L * 512); short* SfL  = salloc(511L * 512);
    short* CSH  = salloc(510L * 1024); short* CSL  = salloc(510L * 1024);
    short* CS2H = salloc(510L * 1024); short* CS2L = salloc(510L * 1024);
    float* xcur = alloc((size_t)cb * NN2);
    float* xnxt = alloc((size_t)cb * NN2);
    float* r1   = alloc((size_t)cb * MM2);
    float* F1c  = alloc((size_t)cb * MM2);
    float* F2c  = alloc((size_t)cb * MM2);
    float* G    = alloc((size_t)cb * HW2);
    float* outRI  = alloc((size_t)cb * 2 * HW2);
    float* outRI2 = alloc((size_t)cb * 2 * HW2);
    short* r1TH = salloc((size_t)cb * 510 * 512); short* r1TL = salloc((size_t)cb * 510 * 512);
    short* T1H  = salloc((size_t)cb * 511 * 512); short* T1L  = salloc((size_t)cb * 511 * 512);
    short* oRTH = salloc((size_t)cb * 511 * 1024); short* oRTL = salloc((size_t)cb * 511 * 1024);
    short* XYH  = salloc((size_t)cb * 510 * 1024); short* XYL  = salloc((size_t)cb * 510 * 1024);

    detect_kernel<<<1, 256, 0, stream>>>(f, dmode);
    zerod_kernel<<<1, 64, 0, stream>>>(acc);
    basisHL_kernel<<<dim3((510 * 1024 + 255) / 256), 256, 0, stream>>>(SfH, SfL, CSH, CSL, CS2H, CS2L);

    dim3 blk(32, 8);
    dim3 gridc(16, 64, cb);
    dim3 cblk(64, 4);
    dim3 ccgrid(8, 64, cb);    // 64x8 output tiles over 511x511
    dim3 tblk(32, 8);

    const long sb_r1T = 510L * 512, sb_T1 = 511L * 512, sb_oRT = 511L * 1024, sb_XY = 510L * 1024;
    const float cfwd = -4.0f / 1044484.0f;  // -4/1022^2

    auto gemmF = [&](const short* AH_, const short* AL_, int ldaS, long asb,
                     const short* BH_, const short* BL_, int ldbS, long bsb,
                     float* C_, int ldc, long csb,
                     int M, int N, int Kpad, float alpha) {
        dim3 g((N + GN - 1) / GN, (M + GM - 1) / GM, cb);
        gemm_hl<<<g, 256, 0, stream>>>(AH_, AL_, ldaS, BH_, BL_, ldbS,
                                       C_, ldc, nullptr, nullptr, 0, 0,
                                       M, N, Kpad, asb, bsb, csb, alpha, 0);
    };
    auto gemmHL = [&](const short* AH_, const short* AL_, int ldaS, long asb,
                      const short* BH_, const short* BL_, int ldbS, long bsb,
                      short* CH_, short* CL_, int ldcS, long csb,
                      int M, int N, int Npad, int Kpad, float alpha) {
        dim3 g((Npad + GN - 1) / GN, (M + GM - 1) / GM, cb);
        gemm_hl<<<g, 256, 0, stream>>>(AH_, AL_, ldaS, BH_, BL_, ldbS,
                                       nullptr, 0, CH_, CL_, ldcS, Npad,
                                       M, N, Kpad, asb, bsb, csb, alpha, 1);
    };

    for (int b0 = 0; b0 < 8; b0 += cb) {
        initx_kernel<<<gridc, blk, 0, stream>>>(xcur, f, b0, dmode);
        float* cur = xcur; float* nxt = xnxt;
        for (int it = 0; it < 9; ++it) {
            rich_kernel<<<gridc, blk, 0, stream>>>(cur, nxt, f, coef, b0, dmode);
            float* t = cur; cur = nxt; nxt = t;
        }
        resid_kernel<<<gridc, blk, 0, stream>>>(cur, f, coef, r1, b0, dmode);

        transposeHL_kernel<<<dim3(16, 16, cb), tblk, 0, stream>>>(
            r1, r1TH, r1TL, MM, MM, MM, 512, 0, 512, MM2, sb_r1T);

        gemmHL(SfH, SfL, 512, 0, r1TH, r1TL, 512, sb_r1T,
               T1H, T1L, 512, sb_T1, 511, 510, 512, 512, 1.f);
        gemmF(T1H, T1L, 512, sb_T1, SfH, SfL, 512, 0,
              G, HW, HW2, 511, 511, 512, cfwd);

        zerocol_kernel<<<cb, 512, 0, stream>>>(XYH, XYL, sb_XY);

        for (int t = 0; t < 2; ++t) {
            // forward chain fused: G(real) -> w1 -> w2 -> w3 (+theta) -> outRI (planar)
            cconv_chain<0, 0, 1><<<ccgrid, cblk, 0, stream>>>(
                G, nullptr, W1r[t], W1i[t], W2r[t], W2i[t], W3r[t], W3i[t],
                outRI, outRI + HW2, THr[t], THi[t],
                HW2, 2L * HW2, b0, dmode);
            // transposed-conj chain fused: outRI -> w3^T -> w2^T -> w1^T -> outRI2 (planar)
            cconv_chain<2, 1, 0><<<ccgrid, cblk, 0, stream>>>(
                outRI, outRI + HW2, W3r[t], W3i[t], W2r[t], W2i[t], W1r[t], W1i[t],
                outRI2, outRI2 + HW2, nullptr, nullptr,
                2L * HW2, 2L * HW2, b0, dmode);

            transposeHL_kernel<<<dim3(16, 16, cb), tblk, 0, stream>>>(
                outRI2, oRTH, oRTL, HW, HW, HW, 1024, 0, 511, 2L * HW2, sb_oRT);
            transposeHL_kernel<<<dim3(16, 17, cb), tblk, 0, stream>>>(
                outRI2 + HW2, oRTH, oRTL, HW, HW, HW, 1024, 511, 513, 2L * HW2, sb_oRT);

            gemmHL(CSH, CSL, 1024, 0, oRTH, oRTL, 1024, sb_oRT,
                   XYH, XYL, 1024, sb_XY, 510, 511, 511, 1024, 1.f);
            gemmHL(CS2H, CS2L, 1024, 0, oRTH, oRTL, 1024, sb_oRT,
                   XYH + 511, XYL + 511, 1024, sb_XY, 510, 511, 512, 1024, 1.f);
            float* Ft = (t == 0) ? F1c : F2c;
            gemmF(XYH, XYL, 1024, sb_XY, CSH, CSL, 1024, 0,
                  Ft, MM, MM2, 510, 510, 1024, 1.f);
        }

        update_kernel<<<gridc, blk, 0, stream>>>(cur, coef, F1c, F2c, b0, dmode);
        norm_kernel<<<gridc, blk, 0, stream>>>(cur, f, coef, pb, b0, dmode);
        reduce_kernel<<<1, 256, 0, stream>>>(pb, (long)1024 * cb, acc);
    }

    finalize_kernel<<<1, 1, 0, stream>>>(acc, (float*)d_out);
}